// Round 11
// baseline (446.073 us; speedup 1.0000x reference)
//
#include <hip/hip_runtime.h>
#include <stdint.h>
#include <math.h>

#define NQ 10000
#define NC 2048
#define NW 157           // ceil(10000/64)
#define NTRI 12403       // NW*(NW+1)/2 upper-triangle blocks
#define TRI_PER_BLK 8
#define NMASKBLK ((NTRI + TRI_PER_BLK - 1) / TRI_PER_BLK)   // 1551
#define IOU_TH 0.5f

// -------- ws layout (bytes) --------
// scores : [0,       40000)
// rank   : [40000,   80000)
// boxes4 : [80000,  240000)   10000*4 f32 (xyxy, clipped+scaled)
// sx1    : [240000, 280000)   sorted SoA
// sy1    : [280000, 320000)
// sx2    : [320000, 360000)
// sy2    : [360000, 400000)
// sarea  : [400000, 440000)
// order  : [440000, 480000)   sorted index -> original index
// mask   : [480000, 480000+10000*157*8 = 13,040,000)

// Fused front-end: blocks 0..2499 = per-query softmax scores; block 2500 =
// cls argmax; blocks 2501..2540 = box convert/clip/scale.
__global__ __launch_bounds__(256) void k_front(const float* __restrict__ logits,
        const float* __restrict__ cls, const float* __restrict__ pb,
        const int* __restrict__ ts,
        float* __restrict__ out_scores, float* __restrict__ out_labels,
        float* __restrict__ out_cls, float* __restrict__ out_boxes,
        float* __restrict__ ws_scores, float* __restrict__ boxes4,
        int* __restrict__ rank) {
    int bx = blockIdx.x;
    if (bx < 2500) {
        int wave = threadIdx.x >> 6;
        int lane = threadIdx.x & 63;
        int q = bx * 4 + wave;
        if (q >= NQ) return;
        const float* row = logits + (size_t)q * NC;
        float4 v[8];
        float m = -3.4e38f;
        int am = 0;
        #pragma unroll
        for (int k = 0; k < 8; k++) {
            int idx = k * 256 + lane * 4;
            v[k] = *(const float4*)(row + idx);
            // strict > keeps first occurrence within this lane's ascending indices
            if (v[k].x > m) { m = v[k].x; am = idx; }
            if (v[k].y > m) { m = v[k].y; am = idx + 1; }
            if (v[k].z > m) { m = v[k].z; am = idx + 2; }
            if (v[k].w > m) { m = v[k].w; am = idx + 3; }
        }
        #pragma unroll
        for (int off = 32; off >= 1; off >>= 1) {
            float om = __shfl_xor(m, off);
            int   oa = __shfl_xor(am, off);
            if (om > m || (om == m && oa < am)) { m = om; am = oa; }
        }
        float s = 0.f;
        #pragma unroll
        for (int k = 0; k < 8; k++) {
            s += expf(v[k].x - m);
            s += expf(v[k].y - m);
            s += expf(v[k].z - m);
            s += expf(v[k].w - m);
        }
        #pragma unroll
        for (int off = 32; off >= 1; off >>= 1) s += __shfl_xor(s, off);
        if (lane == 0) {
            float sc = 1.0f / s;           // max prob = exp(0)/sum = 1/sum
            out_scores[q] = sc;
            out_labels[q] = (float)am;
            ws_scores[q]  = sc;
        }
        return;
    }
    if (bx == 2500) {
        float m = -3.4e38f; int am = 0x7fffffff;
        for (int idx = threadIdx.x; idx < NC; idx += 256) {
            float x = cls[idx];
            if (x > m) { m = x; am = idx; }    // per-thread indices ascending
        }
        int lane = threadIdx.x & 63, wave = threadIdx.x >> 6;
        #pragma unroll
        for (int off = 32; off >= 1; off >>= 1) {
            float om = __shfl_xor(m, off); int oa = __shfl_xor(am, off);
            if (om > m || (om == m && oa < am)) { m = om; am = oa; }
        }
        __shared__ float sm[4]; __shared__ int sa[4];
        if (lane == 0) { sm[wave] = m; sa[wave] = am; }
        __syncthreads();
        if (threadIdx.x == 0) {
            for (int w = 1; w < 4; w++)
                if (sm[w] > m || (sm[w] == m && sa[w] < am)) { m = sm[w]; am = sa[w]; }
            out_cls[0] = (float)am;
        }
        return;
    }
    {
        #pragma clang fp contract(off)
        int i = (bx - 2501) * 256 + threadIdx.x;
        if (i >= NQ) return;
        rank[i] = 0;
        // target_sizes may be int64 (low/high word pairs) or int32; values in [480,1333)
        int a0 = ts[0], a1 = ts[1];
        int ih, iw;
        if (a1 == 0) { ih = a0; iw = ts[2]; } else { ih = a0; iw = a1; }
        float sh = (float)ih, sw = (float)iw;
        float4 b = *(const float4*)(pb + i * 4);
        float x1 = b.x - 0.5f * b.z;
        float y1 = b.y - 0.5f * b.w;
        float x2 = b.x + 0.5f * b.z;
        float y2 = b.y + 0.5f * b.w;
        x1 = fminf(fmaxf(x1, 0.f), 1.f) * sw;
        y1 = fminf(fmaxf(y1, 0.f), 1.f) * sh;
        x2 = fminf(fmaxf(x2, 0.f), 1.f) * sw;
        y2 = fminf(fmaxf(y2, 0.f), 1.f) * sh;
        float4 o = make_float4(x1, y1, x2, y2);
        *(float4*)(out_boxes + i * 4) = o;
        *(float4*)(boxes4 + i * 4) = o;
    }
}

// rank[i] = #{j: s_j > s_i} + #{j: s_j == s_i && j < i}  == position in argsort(-s)
__global__ __launch_bounds__(256) void k_count(const float* __restrict__ scores,
                                               int* __restrict__ rank) {
    __shared__ float4 sc4[500];
    int jbase = blockIdx.y * 2000;
    const float4* src = (const float4*)(scores + jbase);
    for (int t = threadIdx.x; t < 500; t += 256) sc4[t] = src[t];
    __syncthreads();
    int i = blockIdx.x * 256 + threadIdx.x;
    if (i >= NQ) return;
    float si = scores[i];
    int cnt = 0;
    #pragma unroll 2
    for (int q = 0; q < 500; q++) {
        float4 v = sc4[q];
        int j = jbase + 4 * q;
        cnt += (v.x > si) || (v.x == si && j     < i);
        cnt += (v.y > si) || (v.y == si && j + 1 < i);
        cnt += (v.z > si) || (v.z == si && j + 2 < i);
        cnt += (v.w > si) || (v.w == si && j + 3 < i);
    }
    if (cnt) atomicAdd(&rank[i], cnt);
}

__global__ __launch_bounds__(256) void k_scatter(const float* __restrict__ boxes4,
        const int* __restrict__ rank, int* __restrict__ order,
        float* __restrict__ sx1, float* __restrict__ sy1,
        float* __restrict__ sx2, float* __restrict__ sy2,
        float* __restrict__ sarea) {
    #pragma clang fp contract(off)
    int i = blockIdx.x * 256 + threadIdx.x;
    if (i >= NQ) return;
    int r = rank[i];
    order[r] = i;
    float4 b = *(const float4*)(boxes4 + i * 4);
    sx1[r] = b.x; sy1[r] = b.y; sx2[r] = b.z; sy2[r] = b.w;
    sarea[r] = fmaxf(b.z - b.x, 0.f) * fmaxf(b.w - b.y, 0.f);
}

// mask[i][cb] bit jj = (j>i) && IoU(i,j)>0.5 (sorted order). 1D upper-triangle
// grid, TRI_PER_BLK consecutive tri-tiles per 64-thread block: the sqrt decode
// runs once, then (rb,cb) increments (tris are row-major in the triangle);
// 12403 -> 1551 dispatched blocks. Single-wave blocks: the LDS-reuse
// __syncthreads are effectively free.
__global__ __launch_bounds__(64) void k_mask(const float* __restrict__ sx1,
        const float* __restrict__ sy1, const float* __restrict__ sx2,
        const float* __restrict__ sy2, const float* __restrict__ sarea,
        unsigned long long* __restrict__ mask) {
    #pragma clang fp contract(off)
    int tri = blockIdx.x * TRI_PER_BLK;
    if (tri >= NTRI) return;
    // decode first tri: S(r) = r*NW - r*(r-1)/2 entries precede row r
    int rb = (int)((2.0 * NW + 1.0
              - sqrt((double)((2 * NW + 1) * (2 * NW + 1) - 8 * tri))) * 0.5);
    while (rb > 0 && rb * NW - rb * (rb - 1) / 2 > tri) rb--;
    while ((rb + 1) * NW - (rb + 1) * rb / 2 <= tri) rb++;
    int cb = rb + (tri - (rb * NW - rb * (rb - 1) / 2));

    int t = threadIdx.x;
    __shared__ float cx1[64], cy1[64], cx2[64], cy2[64], ca[64];

    #pragma unroll 1
    for (int s = 0; s < TRI_PER_BLK; s++, tri++) {
        if (tri >= NTRI) return;
        __syncthreads();   // previous iteration's LDS reads complete (1-wave: ~free)
        int j0 = cb * 64 + t;
        if (j0 < NQ) { cx1[t]=sx1[j0]; cy1[t]=sy1[j0]; cx2[t]=sx2[j0]; cy2[t]=sy2[j0]; ca[t]=sarea[j0]; }
        __syncthreads();
        int i = rb * 64 + t;
        if (i < NQ) {
            float xi1 = sx1[i], yi1 = sy1[i], xi2 = sx2[i], yi2 = sy2[i], ai = sarea[i];
            int ncol = min(64, NQ - cb * 64);
            unsigned long long word = 0;
            for (int jj = 0; jj < ncol; jj++) {
                int j = cb * 64 + jj;
                float lx = fmaxf(xi1, cx1[jj]);
                float ly = fmaxf(yi1, cy1[jj]);
                float rx = fminf(xi2, cx2[jj]);
                float ry = fminf(yi2, cy2[jj]);
                float w = fmaxf(rx - lx, 0.f);
                float h = fmaxf(ry - ly, 0.f);
                float inter = w * h;
                float denom = (ai + ca[jj]) - inter;   // ref op order: (areas[i]+areas)-inter
                float iou = inter / denom;
                bool sup = (iou > IOU_TH) && (j > i);
                word |= ((unsigned long long)(sup ? 1u : 0u)) << jj;
            }
            mask[(size_t)i * NW + cb] = word;
        }
        // step to next tri (row-major upper triangle)
        cb++;
        if (cb >= NW) { rb++; cb = rb; }
    }
}

__device__ __forceinline__ unsigned long long bcast64(unsigned long long v) {
    uint32_t lo = (uint32_t)__builtin_amdgcn_readfirstlane((int)(uint32_t)v);
    uint32_t hi = (uint32_t)__builtin_amdgcn_readfirstlane((int)(uint32_t)(v >> 32));
    return ((unsigned long long)hi << 32) | lo;
}

__device__ __forceinline__ uint64_t rl64(uint32_t lo, uint32_t hi, int b) {
    return ((uint64_t)(uint32_t)__builtin_amdgcn_readlane((int)hi, b) << 32)
         | (uint32_t)__builtin_amdgcn_readlane((int)lo, b);
}

// Greedy reduce, v10 (FROZEN): best-measured scan (209us). Seven structural
// variants (v6..v11: 204/209/211/215/216/232) bracket a hard ~205-210us floor
// = 157 x {serial greedy resolve + 2 barriers + LDS round trips} at the idle
// single-WG clock. Asm-pinned loads (v11) proved the L3 latency is already
// overlapped; batching/barrier-topology/readlane-shortening all neutral.
// See v10's correctness audit (R9) for the batch-4 resolve proof and the
// crit-word shuffle-reduce race audit.
__global__ __launch_bounds__(256, 1) void k_scan(const unsigned long long* __restrict__ mask,
        const int* __restrict__ order, float* __restrict__ out_keep) {
    __shared__ unsigned long long rem[NW];
    __shared__ unsigned long long keepw[NW];
    __shared__ unsigned long long dgbuf[2][64]; // diag word, chunk parity buffers
    __shared__ unsigned long long ccbuf[2][64]; // critical column (word c+1), parity buffers
    __shared__ unsigned long long sh_kept;

    const int tid  = threadIdx.x;
    const int wave = tid >> 6;
    const int lane = tid & 63;

    for (int w = tid; w < NW; w += 256) rem[w] = 0;

    // prologue: wave 0 stages chunk 0's diag (word 0) + critical column (word 1)
    if (wave == 0) {
        const unsigned long long* rp = mask + (size_t)lane * NW;
        dgbuf[0][lane] = rp[0];
        ccbuf[0][lane] = rp[1];
    }
    __syncthreads();

    // per-thread pending bulk state (waves 1-3)
    uint64_t p0=0,p1=0,p2=0,p3=0,p4=0,p5=0,p6=0,p7=0;
    uint64_t p8=0,p9=0,p10=0,p11=0,p12=0,p13=0,p14=0,p15=0;
    uint64_t pextra = 0;
    int pw = -1;

    for (int c = 0; c < NW; c++) {
        // ======================= phase A =======================
        uint64_t dn = 0, ccn = 0;
        if (wave == 0) {
            // issue next chunk's diag + critical-column loads FIRST (latency
            // hidden under resolve + critical; stored to LDS at end of B)
            if (c + 1 < NW) {
                int i2 = (c + 1) * 64 + lane;
                if (i2 < NQ) {
                    const unsigned long long* rp = mask + (size_t)i2 * NW;
                    dn = rp[c + 1];
                    if (c + 2 < NW) ccn = rp[c + 2];
                }
            }
            // serial greedy resolve, batch-4 (SGPR-disciplined)
            uint64_t cur = bcast64(rem[c]);
            int nvalid = min(64, NQ - c * 64);
            if (nvalid < 64) cur |= (~0ull) << nvalid;   // invalid tail = suppressed

            uint64_t dgv = dgbuf[c & 1][lane];
            uint32_t dvlo = (uint32_t)dgv, dvhi = (uint32_t)(dgv >> 32);

            uint64_t alive = ~cur;
            uint64_t kept  = 0;
            while (alive) {
                uint64_t t0 = alive;
                int b0 = (int)__builtin_ctzll(t0); t0 &= t0 - 1;
                int b1 = t0 ? (int)__builtin_ctzll(t0) : b0; t0 &= t0 - 1;
                int b2 = t0 ? (int)__builtin_ctzll(t0) : b0; t0 &= t0 - 1;
                int b3 = t0 ? (int)__builtin_ctzll(t0) : b0;
                uint64_t d0 = rl64(dvlo, dvhi, b0);
                uint64_t d1 = rl64(dvlo, dvhi, b1);
                uint64_t d2 = rl64(dvlo, dvhi, b2);
                uint64_t d3 = rl64(dvlo, dvhi, b3);
                uint64_t sup = d0;
                kept |= 1ull << b0;
                if (!((sup >> b1) & 1ull)) { kept |= 1ull << b1; sup |= d1; }
                if (!((sup >> b2) & 1ull)) { kept |= 1ull << b2; sup |= d2; }
                if (!((sup >> b3) & 1ull)) { kept |= 1ull << b3; sup |= d3; }
                cur   |= sup;
                alive &= ~(sup | (1ull << b0) | (1ull << b1) | (1ull << b2) | (1ull << b3));
            }
            if (tid == 0) { sh_kept = kept; keepw[c] = cur; }
        } else {
            // consume pending bulk(c-1): loads sink to here; stall overlaps
            // wave0's resolve
            if (pw >= 0) {
                uint64_t pacc = ((p0|p1)|(p2|p3)) | ((p4|p5)|(p6|p7));
                pacc |= ((p8|p9)|(p10|p11)) | ((p12|p13)|(p14|p15));
                pacc |= pextra;
                if (pacc) atomicOr(&rem[pw], (unsigned long long)pacc);
            }
            pw = -1;
        }
        __syncthreads();   // barrier 1: sh_kept / keepw[c] published

        // ======================= phase B =======================
        uint64_t kts = bcast64(sh_kept);

        if (wave == 0) {
            if (c + 1 < NW) {
                // critical word c+1: masked shuffle-OR reduce + single-lane RMW
                uint64_t ccv = ccbuf[c & 1][lane];
                uint64_t m = ((kts >> lane) & 1ull) ? ccv : 0;
                #pragma unroll
                for (int off = 32; off >= 1; off >>= 1) m |= __shfl_xor(m, off);
                if (lane == 0) rem[c + 1] |= m;    // sole phase-B rem writer
                // stage next chunk's buffers (waits on dn/ccn: ~a resolve old)
                dgbuf[(c + 1) & 1][lane] = dn;
                if (c + 2 < NW) ccbuf[(c + 1) & 1][lane] = ccn;
            }
        } else {
            // bulk issue: thread t owns word w = c+2+(t-64)
            int w = c + 2 + (tid - 64);
            if (kts && w < NW) {
                const unsigned long long* base = mask + (size_t)(c * 64) * NW + w;
                uint64_t km = kts;
                int r_first = (int)__builtin_ctzll(km);
                int r;
                // 16 named slots, padded with r_first (OR-idempotent duplicate)
                r = km ? (int)__builtin_ctzll(km) : r_first; if (km) km &= km - 1; p0  = base[(size_t)r * NW];
                r = km ? (int)__builtin_ctzll(km) : r_first; if (km) km &= km - 1; p1  = base[(size_t)r * NW];
                r = km ? (int)__builtin_ctzll(km) : r_first; if (km) km &= km - 1; p2  = base[(size_t)r * NW];
                r = km ? (int)__builtin_ctzll(km) : r_first; if (km) km &= km - 1; p3  = base[(size_t)r * NW];
                r = km ? (int)__builtin_ctzll(km) : r_first; if (km) km &= km - 1; p4  = base[(size_t)r * NW];
                r = km ? (int)__builtin_ctzll(km) : r_first; if (km) km &= km - 1; p5  = base[(size_t)r * NW];
                r = km ? (int)__builtin_ctzll(km) : r_first; if (km) km &= km - 1; p6  = base[(size_t)r * NW];
                r = km ? (int)__builtin_ctzll(km) : r_first; if (km) km &= km - 1; p7  = base[(size_t)r * NW];
                r = km ? (int)__builtin_ctzll(km) : r_first; if (km) km &= km - 1; p8  = base[(size_t)r * NW];
                r = km ? (int)__builtin_ctzll(km) : r_first; if (km) km &= km - 1; p9  = base[(size_t)r * NW];
                r = km ? (int)__builtin_ctzll(km) : r_first; if (km) km &= km - 1; p10 = base[(size_t)r * NW];
                r = km ? (int)__builtin_ctzll(km) : r_first; if (km) km &= km - 1; p11 = base[(size_t)r * NW];
                r = km ? (int)__builtin_ctzll(km) : r_first; if (km) km &= km - 1; p12 = base[(size_t)r * NW];
                r = km ? (int)__builtin_ctzll(km) : r_first; if (km) km &= km - 1; p13 = base[(size_t)r * NW];
                r = km ? (int)__builtin_ctzll(km) : r_first; if (km) km &= km - 1; p14 = base[(size_t)r * NW];
                r = km ? (int)__builtin_ctzll(km) : r_first; if (km) km &= km - 1; p15 = base[(size_t)r * NW];
                // overflow kept>16 (early chunks): exposed 8-wide batches
                pextra = 0;
                while (km) {
                    uint64_t x0=0,x1=0,x2=0,x3=0,x4=0,x5=0,x6=0,x7=0;
                    if (km) { r=(int)__builtin_ctzll(km); km&=km-1; x0=base[(size_t)r*NW]; }
                    if (km) { r=(int)__builtin_ctzll(km); km&=km-1; x1=base[(size_t)r*NW]; }
                    if (km) { r=(int)__builtin_ctzll(km); km&=km-1; x2=base[(size_t)r*NW]; }
                    if (km) { r=(int)__builtin_ctzll(km); km&=km-1; x3=base[(size_t)r*NW]; }
                    if (km) { r=(int)__builtin_ctzll(km); km&=km-1; x4=base[(size_t)r*NW]; }
                    if (km) { r=(int)__builtin_ctzll(km); km&=km-1; x5=base[(size_t)r*NW]; }
                    if (km) { r=(int)__builtin_ctzll(km); km&=km-1; x6=base[(size_t)r*NW]; }
                    if (km) { r=(int)__builtin_ctzll(km); km&=km-1; x7=base[(size_t)r*NW]; }
                    pextra |= (x0|x1)|(x2|x3)|((x4|x5)|(x6|x7));
                }
                pw = w;
            } else {
                pw = -1; pextra = 0;
            }
        }
        __syncthreads();   // barrier 2: rem[c+1] complete; LDS buffers staged
    }

    // ================= epilogue: parallel keep writeback =================
    for (int si = tid; si < NQ; si += 256) {
        unsigned long long kw = keepw[si >> 6];
        out_keep[order[si]] = ((kw >> (si & 63)) & 1ull) ? 0.f : 1.f;
    }
}

extern "C" void kernel_launch(void* const* d_in, const int* in_sizes, int n_in,
                              void* d_out, int out_size, void* d_ws, size_t ws_size,
                              hipStream_t stream) {
    const float* pred_logits = (const float*)d_in[0];
    const float* pred_boxes  = (const float*)d_in[1];
    const float* cls_logits  = (const float*)d_in[2];
    const int*   tsizes      = (const int*)d_in[3];

    float* out = (float*)d_out;
    float* out_scores = out;
    float* out_labels = out + 10000;
    float* out_boxes  = out + 20000;
    float* out_keep   = out + 60000;
    float* out_cls    = out + 70000;

    char* ws = (char*)d_ws;
    float* ws_scores = (float*)(ws + 0);
    int*   rank      = (int*)  (ws + 40000);
    float* boxes4    = (float*)(ws + 80000);
    float* sx1       = (float*)(ws + 240000);
    float* sy1       = (float*)(ws + 280000);
    float* sx2       = (float*)(ws + 320000);
    float* sy2       = (float*)(ws + 360000);
    float* sarea     = (float*)(ws + 400000);
    int*   order     = (int*)  (ws + 440000);
    unsigned long long* mask = (unsigned long long*)(ws + 480000);

    k_front<<<2541, 256, 0, stream>>>(pred_logits, cls_logits, pred_boxes, tsizes,
                                      out_scores, out_labels, out_cls, out_boxes,
                                      ws_scores, boxes4, rank);
    k_count<<<dim3(40, 5), 256, 0, stream>>>(ws_scores, rank);
    k_scatter<<<40, 256, 0, stream>>>(boxes4, rank, order, sx1, sy1, sx2, sy2, sarea);
    k_mask<<<NMASKBLK, 64, 0, stream>>>(sx1, sy1, sx2, sy2, sarea, mask);
    k_scan<<<1, 256, 0, stream>>>(mask, order, out_keep);
}

// Round 12
// 418.151 us; speedup vs baseline: 1.0668x; 1.0668x over previous
//
#include <hip/hip_runtime.h>
#include <stdint.h>
#include <math.h>

#define NQ 10000
#define NC 2048
#define NW 157           // ceil(10000/64)
#define NTRI 12403       // NW*(NW+1)/2 upper-triangle blocks
#define IOU_TH 0.5f

// -------- ws layout (bytes) --------
// scores : [0,       40000)
// rank   : [40000,   80000)
// boxes4 : [80000,  240000)   10000*4 f32 (xyxy, clipped+scaled)
// sx1    : [240000, 280000)   sorted SoA
// sy1    : [280000, 320000)
// sx2    : [320000, 360000)
// sy2    : [360000, 400000)
// sarea  : [400000, 440000)
// order  : [440000, 480000)   sorted index -> original index
// mask   : [480000, 480000+10000*157*8 = 13,040,000)

// Fused front-end: blocks 0..2499 = per-query softmax scores; block 2500 =
// cls argmax; blocks 2501..2540 = box convert/clip/scale.
__global__ __launch_bounds__(256) void k_front(const float* __restrict__ logits,
        const float* __restrict__ cls, const float* __restrict__ pb,
        const int* __restrict__ ts,
        float* __restrict__ out_scores, float* __restrict__ out_labels,
        float* __restrict__ out_cls, float* __restrict__ out_boxes,
        float* __restrict__ ws_scores, float* __restrict__ boxes4,
        int* __restrict__ rank) {
    int bx = blockIdx.x;
    if (bx < 2500) {
        int wave = threadIdx.x >> 6;
        int lane = threadIdx.x & 63;
        int q = bx * 4 + wave;
        if (q >= NQ) return;
        const float* row = logits + (size_t)q * NC;
        float4 v[8];
        float m = -3.4e38f;
        int am = 0;
        #pragma unroll
        for (int k = 0; k < 8; k++) {
            int idx = k * 256 + lane * 4;
            v[k] = *(const float4*)(row + idx);
            // strict > keeps first occurrence within this lane's ascending indices
            if (v[k].x > m) { m = v[k].x; am = idx; }
            if (v[k].y > m) { m = v[k].y; am = idx + 1; }
            if (v[k].z > m) { m = v[k].z; am = idx + 2; }
            if (v[k].w > m) { m = v[k].w; am = idx + 3; }
        }
        #pragma unroll
        for (int off = 32; off >= 1; off >>= 1) {
            float om = __shfl_xor(m, off);
            int   oa = __shfl_xor(am, off);
            if (om > m || (om == m && oa < am)) { m = om; am = oa; }
        }
        float s = 0.f;
        #pragma unroll
        for (int k = 0; k < 8; k++) {
            s += expf(v[k].x - m);
            s += expf(v[k].y - m);
            s += expf(v[k].z - m);
            s += expf(v[k].w - m);
        }
        #pragma unroll
        for (int off = 32; off >= 1; off >>= 1) s += __shfl_xor(s, off);
        if (lane == 0) {
            float sc = 1.0f / s;           // max prob = exp(0)/sum = 1/sum
            out_scores[q] = sc;
            out_labels[q] = (float)am;
            ws_scores[q]  = sc;
        }
        return;
    }
    if (bx == 2500) {
        float m = -3.4e38f; int am = 0x7fffffff;
        for (int idx = threadIdx.x; idx < NC; idx += 256) {
            float x = cls[idx];
            if (x > m) { m = x; am = idx; }    // per-thread indices ascending
        }
        int lane = threadIdx.x & 63, wave = threadIdx.x >> 6;
        #pragma unroll
        for (int off = 32; off >= 1; off >>= 1) {
            float om = __shfl_xor(m, off); int oa = __shfl_xor(am, off);
            if (om > m || (om == m && oa < am)) { m = om; am = oa; }
        }
        __shared__ float sm[4]; __shared__ int sa[4];
        if (lane == 0) { sm[wave] = m; sa[wave] = am; }
        __syncthreads();
        if (threadIdx.x == 0) {
            for (int w = 1; w < 4; w++)
                if (sm[w] > m || (sm[w] == m && sa[w] < am)) { m = sm[w]; am = sa[w]; }
            out_cls[0] = (float)am;
        }
        return;
    }
    {
        #pragma clang fp contract(off)
        int i = (bx - 2501) * 256 + threadIdx.x;
        if (i >= NQ) return;
        rank[i] = 0;
        // target_sizes may be int64 (low/high word pairs) or int32; values in [480,1333)
        int a0 = ts[0], a1 = ts[1];
        int ih, iw;
        if (a1 == 0) { ih = a0; iw = ts[2]; } else { ih = a0; iw = a1; }
        float sh = (float)ih, sw = (float)iw;
        float4 b = *(const float4*)(pb + i * 4);
        float x1 = b.x - 0.5f * b.z;
        float y1 = b.y - 0.5f * b.w;
        float x2 = b.x + 0.5f * b.z;
        float y2 = b.y + 0.5f * b.w;
        x1 = fminf(fmaxf(x1, 0.f), 1.f) * sw;
        y1 = fminf(fmaxf(y1, 0.f), 1.f) * sh;
        x2 = fminf(fmaxf(x2, 0.f), 1.f) * sw;
        y2 = fminf(fmaxf(y2, 0.f), 1.f) * sh;
        float4 o = make_float4(x1, y1, x2, y2);
        *(float4*)(out_boxes + i * 4) = o;
        *(float4*)(boxes4 + i * 4) = o;
    }
}

// rank[i] = #{j: s_j > s_i} + #{j: s_j == s_i && j < i}  == position in argsort(-s)
__global__ __launch_bounds__(256) void k_count(const float* __restrict__ scores,
                                               int* __restrict__ rank) {
    __shared__ float4 sc4[500];
    int jbase = blockIdx.y * 2000;
    const float4* src = (const float4*)(scores + jbase);
    for (int t = threadIdx.x; t < 500; t += 256) sc4[t] = src[t];
    __syncthreads();
    int i = blockIdx.x * 256 + threadIdx.x;
    if (i >= NQ) return;
    float si = scores[i];
    int cnt = 0;
    #pragma unroll 2
    for (int q = 0; q < 500; q++) {
        float4 v = sc4[q];
        int j = jbase + 4 * q;
        cnt += (v.x > si) || (v.x == si && j     < i);
        cnt += (v.y > si) || (v.y == si && j + 1 < i);
        cnt += (v.z > si) || (v.z == si && j + 2 < i);
        cnt += (v.w > si) || (v.w == si && j + 3 < i);
    }
    if (cnt) atomicAdd(&rank[i], cnt);
}

__global__ __launch_bounds__(256) void k_scatter(const float* __restrict__ boxes4,
        const int* __restrict__ rank, int* __restrict__ order,
        float* __restrict__ sx1, float* __restrict__ sy1,
        float* __restrict__ sx2, float* __restrict__ sy2,
        float* __restrict__ sarea) {
    #pragma clang fp contract(off)
    int i = blockIdx.x * 256 + threadIdx.x;
    if (i >= NQ) return;
    int r = rank[i];
    order[r] = i;
    float4 b = *(const float4*)(boxes4 + i * 4);
    sx1[r] = b.x; sy1[r] = b.y; sx2[r] = b.z; sy2[r] = b.w;
    sarea[r] = fmaxf(b.z - b.x, 0.f) * fmaxf(b.w - b.y, 0.f);
}

// mask[i][cb] bit jj = (j>i) && IoU(i,j)>0.5 (sorted order). 1D upper-triangle
// grid, ONE tri per 64-thread block (R11 showed batching tiles serializes
// work that was previously dispatch-parallel: 8x fewer blocks = 8x longer
// critical path, +25us).
__global__ __launch_bounds__(64) void k_mask(const float* __restrict__ sx1,
        const float* __restrict__ sy1, const float* __restrict__ sx2,
        const float* __restrict__ sy2, const float* __restrict__ sarea,
        unsigned long long* __restrict__ mask) {
    #pragma clang fp contract(off)
    int tri = blockIdx.x;
    int rb = (int)((2.0 * NW + 1.0
              - sqrt((double)((2 * NW + 1) * (2 * NW + 1) - 8 * tri))) * 0.5);
    while (rb > 0 && rb * NW - rb * (rb - 1) / 2 > tri) rb--;
    while ((rb + 1) * NW - (rb + 1) * rb / 2 <= tri) rb++;
    int cb = rb + (tri - (rb * NW - rb * (rb - 1) / 2));

    int t = threadIdx.x;
    __shared__ float cx1[64], cy1[64], cx2[64], cy2[64], ca[64];
    int j0 = cb * 64 + t;
    if (j0 < NQ) { cx1[t]=sx1[j0]; cy1[t]=sy1[j0]; cx2[t]=sx2[j0]; cy2[t]=sy2[j0]; ca[t]=sarea[j0]; }
    __syncthreads();
    int i = rb * 64 + t;
    if (i >= NQ) return;
    float xi1 = sx1[i], yi1 = sy1[i], xi2 = sx2[i], yi2 = sy2[i], ai = sarea[i];
    int ncol = min(64, NQ - cb * 64);
    unsigned long long word = 0;
    for (int jj = 0; jj < ncol; jj++) {
        int j = cb * 64 + jj;
        float lx = fmaxf(xi1, cx1[jj]);
        float ly = fmaxf(yi1, cy1[jj]);
        float rx = fminf(xi2, cx2[jj]);
        float ry = fminf(yi2, cy2[jj]);
        float w = fmaxf(rx - lx, 0.f);
        float h = fmaxf(ry - ly, 0.f);
        float inter = w * h;
        float denom = (ai + ca[jj]) - inter;   // ref op order: (areas[i]+areas)-inter
        float iou = inter / denom;
        bool sup = (iou > IOU_TH) && (j > i);
        word |= ((unsigned long long)(sup ? 1u : 0u)) << jj;
    }
    mask[(size_t)i * NW + cb] = word;
}

__device__ __forceinline__ unsigned long long bcast64(unsigned long long v) {
    uint32_t lo = (uint32_t)__builtin_amdgcn_readfirstlane((int)(uint32_t)v);
    uint32_t hi = (uint32_t)__builtin_amdgcn_readfirstlane((int)(uint32_t)(v >> 32));
    return ((unsigned long long)hi << 32) | lo;
}

__device__ __forceinline__ uint64_t rl64(uint32_t lo, uint32_t hi, int b) {
    return ((uint64_t)(uint32_t)__builtin_amdgcn_readlane((int)hi, b) << 32)
         | (uint32_t)__builtin_amdgcn_readlane((int)lo, b);
}

// Greedy reduce, v10 (FROZEN): best-measured scan (~209us). Seven structural
// variants (v6..v11: 204/209/211/215/216/232) bracket a hard ~205-210us floor
// = 157 x {serial greedy resolve + 2 barriers + LDS round trips} at the idle
// single-WG clock. Asm-pinned loads (v11) proved the L3 latency is already
// overlapped; batching/barrier-topology/readlane-shortening all neutral.
// See v10's correctness audit (R9) for the batch-4 resolve proof and the
// crit-word shuffle-reduce race audit.
__global__ __launch_bounds__(256, 1) void k_scan(const unsigned long long* __restrict__ mask,
        const int* __restrict__ order, float* __restrict__ out_keep) {
    __shared__ unsigned long long rem[NW];
    __shared__ unsigned long long keepw[NW];
    __shared__ unsigned long long dgbuf[2][64]; // diag word, chunk parity buffers
    __shared__ unsigned long long ccbuf[2][64]; // critical column (word c+1), parity buffers
    __shared__ unsigned long long sh_kept;

    const int tid  = threadIdx.x;
    const int wave = tid >> 6;
    const int lane = tid & 63;

    for (int w = tid; w < NW; w += 256) rem[w] = 0;

    // prologue: wave 0 stages chunk 0's diag (word 0) + critical column (word 1)
    if (wave == 0) {
        const unsigned long long* rp = mask + (size_t)lane * NW;
        dgbuf[0][lane] = rp[0];
        ccbuf[0][lane] = rp[1];
    }
    __syncthreads();

    // per-thread pending bulk state (waves 1-3)
    uint64_t p0=0,p1=0,p2=0,p3=0,p4=0,p5=0,p6=0,p7=0;
    uint64_t p8=0,p9=0,p10=0,p11=0,p12=0,p13=0,p14=0,p15=0;
    uint64_t pextra = 0;
    int pw = -1;

    for (int c = 0; c < NW; c++) {
        // ======================= phase A =======================
        uint64_t dn = 0, ccn = 0;
        if (wave == 0) {
            // issue next chunk's diag + critical-column loads FIRST (latency
            // hidden under resolve + critical; stored to LDS at end of B)
            if (c + 1 < NW) {
                int i2 = (c + 1) * 64 + lane;
                if (i2 < NQ) {
                    const unsigned long long* rp = mask + (size_t)i2 * NW;
                    dn = rp[c + 1];
                    if (c + 2 < NW) ccn = rp[c + 2];
                }
            }
            // serial greedy resolve, batch-4 (SGPR-disciplined)
            uint64_t cur = bcast64(rem[c]);
            int nvalid = min(64, NQ - c * 64);
            if (nvalid < 64) cur |= (~0ull) << nvalid;   // invalid tail = suppressed

            uint64_t dgv = dgbuf[c & 1][lane];
            uint32_t dvlo = (uint32_t)dgv, dvhi = (uint32_t)(dgv >> 32);

            uint64_t alive = ~cur;
            uint64_t kept  = 0;
            while (alive) {
                uint64_t t0 = alive;
                int b0 = (int)__builtin_ctzll(t0); t0 &= t0 - 1;
                int b1 = t0 ? (int)__builtin_ctzll(t0) : b0; t0 &= t0 - 1;
                int b2 = t0 ? (int)__builtin_ctzll(t0) : b0; t0 &= t0 - 1;
                int b3 = t0 ? (int)__builtin_ctzll(t0) : b0;
                uint64_t d0 = rl64(dvlo, dvhi, b0);
                uint64_t d1 = rl64(dvlo, dvhi, b1);
                uint64_t d2 = rl64(dvlo, dvhi, b2);
                uint64_t d3 = rl64(dvlo, dvhi, b3);
                uint64_t sup = d0;
                kept |= 1ull << b0;
                if (!((sup >> b1) & 1ull)) { kept |= 1ull << b1; sup |= d1; }
                if (!((sup >> b2) & 1ull)) { kept |= 1ull << b2; sup |= d2; }
                if (!((sup >> b3) & 1ull)) { kept |= 1ull << b3; sup |= d3; }
                cur   |= sup;
                alive &= ~(sup | (1ull << b0) | (1ull << b1) | (1ull << b2) | (1ull << b3));
            }
            if (tid == 0) { sh_kept = kept; keepw[c] = cur; }
        } else {
            // consume pending bulk(c-1): loads sink to here; stall overlaps
            // wave0's resolve
            if (pw >= 0) {
                uint64_t pacc = ((p0|p1)|(p2|p3)) | ((p4|p5)|(p6|p7));
                pacc |= ((p8|p9)|(p10|p11)) | ((p12|p13)|(p14|p15));
                pacc |= pextra;
                if (pacc) atomicOr(&rem[pw], (unsigned long long)pacc);
            }
            pw = -1;
        }
        __syncthreads();   // barrier 1: sh_kept / keepw[c] published

        // ======================= phase B =======================
        uint64_t kts = bcast64(sh_kept);

        if (wave == 0) {
            if (c + 1 < NW) {
                // critical word c+1: masked shuffle-OR reduce + single-lane RMW
                uint64_t ccv = ccbuf[c & 1][lane];
                uint64_t m = ((kts >> lane) & 1ull) ? ccv : 0;
                #pragma unroll
                for (int off = 32; off >= 1; off >>= 1) m |= __shfl_xor(m, off);
                if (lane == 0) rem[c + 1] |= m;    // sole phase-B rem writer
                // stage next chunk's buffers (waits on dn/ccn: ~a resolve old)
                dgbuf[(c + 1) & 1][lane] = dn;
                if (c + 2 < NW) ccbuf[(c + 1) & 1][lane] = ccn;
            }
        } else {
            // bulk issue: thread t owns word w = c+2+(t-64)
            int w = c + 2 + (tid - 64);
            if (kts && w < NW) {
                const unsigned long long* base = mask + (size_t)(c * 64) * NW + w;
                uint64_t km = kts;
                int r_first = (int)__builtin_ctzll(km);
                int r;
                // 16 named slots, padded with r_first (OR-idempotent duplicate)
                r = km ? (int)__builtin_ctzll(km) : r_first; if (km) km &= km - 1; p0  = base[(size_t)r * NW];
                r = km ? (int)__builtin_ctzll(km) : r_first; if (km) km &= km - 1; p1  = base[(size_t)r * NW];
                r = km ? (int)__builtin_ctzll(km) : r_first; if (km) km &= km - 1; p2  = base[(size_t)r * NW];
                r = km ? (int)__builtin_ctzll(km) : r_first; if (km) km &= km - 1; p3  = base[(size_t)r * NW];
                r = km ? (int)__builtin_ctzll(km) : r_first; if (km) km &= km - 1; p4  = base[(size_t)r * NW];
                r = km ? (int)__builtin_ctzll(km) : r_first; if (km) km &= km - 1; p5  = base[(size_t)r * NW];
                r = km ? (int)__builtin_ctzll(km) : r_first; if (km) km &= km - 1; p6  = base[(size_t)r * NW];
                r = km ? (int)__builtin_ctzll(km) : r_first; if (km) km &= km - 1; p7  = base[(size_t)r * NW];
                r = km ? (int)__builtin_ctzll(km) : r_first; if (km) km &= km - 1; p8  = base[(size_t)r * NW];
                r = km ? (int)__builtin_ctzll(km) : r_first; if (km) km &= km - 1; p9  = base[(size_t)r * NW];
                r = km ? (int)__builtin_ctzll(km) : r_first; if (km) km &= km - 1; p10 = base[(size_t)r * NW];
                r = km ? (int)__builtin_ctzll(km) : r_first; if (km) km &= km - 1; p11 = base[(size_t)r * NW];
                r = km ? (int)__builtin_ctzll(km) : r_first; if (km) km &= km - 1; p12 = base[(size_t)r * NW];
                r = km ? (int)__builtin_ctzll(km) : r_first; if (km) km &= km - 1; p13 = base[(size_t)r * NW];
                r = km ? (int)__builtin_ctzll(km) : r_first; if (km) km &= km - 1; p14 = base[(size_t)r * NW];
                r = km ? (int)__builtin_ctzll(km) : r_first; if (km) km &= km - 1; p15 = base[(size_t)r * NW];
                // overflow kept>16 (early chunks): exposed 8-wide batches
                pextra = 0;
                while (km) {
                    uint64_t x0=0,x1=0,x2=0,x3=0,x4=0,x5=0,x6=0,x7=0;
                    if (km) { r=(int)__builtin_ctzll(km); km&=km-1; x0=base[(size_t)r*NW]; }
                    if (km) { r=(int)__builtin_ctzll(km); km&=km-1; x1=base[(size_t)r*NW]; }
                    if (km) { r=(int)__builtin_ctzll(km); km&=km-1; x2=base[(size_t)r*NW]; }
                    if (km) { r=(int)__builtin_ctzll(km); km&=km-1; x3=base[(size_t)r*NW]; }
                    if (km) { r=(int)__builtin_ctzll(km); km&=km-1; x4=base[(size_t)r*NW]; }
                    if (km) { r=(int)__builtin_ctzll(km); km&=km-1; x5=base[(size_t)r*NW]; }
                    if (km) { r=(int)__builtin_ctzll(km); km&=km-1; x6=base[(size_t)r*NW]; }
                    if (km) { r=(int)__builtin_ctzll(km); km&=km-1; x7=base[(size_t)r*NW]; }
                    pextra |= (x0|x1)|(x2|x3)|((x4|x5)|(x6|x7));
                }
                pw = w;
            } else {
                pw = -1; pextra = 0;
            }
        }
        __syncthreads();   // barrier 2: rem[c+1] complete; LDS buffers staged
    }

    // ================= epilogue: parallel keep writeback =================
    for (int si = tid; si < NQ; si += 256) {
        unsigned long long kw = keepw[si >> 6];
        out_keep[order[si]] = ((kw >> (si & 63)) & 1ull) ? 0.f : 1.f;
    }
}

extern "C" void kernel_launch(void* const* d_in, const int* in_sizes, int n_in,
                              void* d_out, int out_size, void* d_ws, size_t ws_size,
                              hipStream_t stream) {
    const float* pred_logits = (const float*)d_in[0];
    const float* pred_boxes  = (const float*)d_in[1];
    const float* cls_logits  = (const float*)d_in[2];
    const int*   tsizes      = (const int*)d_in[3];

    float* out = (float*)d_out;
    float* out_scores = out;
    float* out_labels = out + 10000;
    float* out_boxes  = out + 20000;
    float* out_keep   = out + 60000;
    float* out_cls    = out + 70000;

    char* ws = (char*)d_ws;
    float* ws_scores = (float*)(ws + 0);
    int*   rank      = (int*)  (ws + 40000);
    float* boxes4    = (float*)(ws + 80000);
    float* sx1       = (float*)(ws + 240000);
    float* sy1       = (float*)(ws + 280000);
    float* sx2       = (float*)(ws + 320000);
    float* sy2       = (float*)(ws + 360000);
    float* sarea     = (float*)(ws + 400000);
    int*   order     = (int*)  (ws + 440000);
    unsigned long long* mask = (unsigned long long*)(ws + 480000);

    k_front<<<2541, 256, 0, stream>>>(pred_logits, cls_logits, pred_boxes, tsizes,
                                      out_scores, out_labels, out_cls, out_boxes,
                                      ws_scores, boxes4, rank);
    k_count<<<dim3(40, 5), 256, 0, stream>>>(ws_scores, rank);
    k_scatter<<<40, 256, 0, stream>>>(boxes4, rank, order, sx1, sy1, sx2, sy2, sarea);
    k_mask<<<NTRI, 64, 0, stream>>>(sx1, sy1, sx2, sy2, sarea, mask);
    k_scan<<<1, 256, 0, stream>>>(mask, order, out_keep);
}